// Round 6
// baseline (172.980 us; speedup 1.0000x reference)
//
#include <hip/hip_runtime.h>
#include <cmath>

#define WIN 11
#define HALO 5
#define IMG 512
#define NIMG 48
#define TSX 64                        /* output tile: 64 wide */
#define TSY 32                        /* x 32 tall */
#define HR (TSY + 2*HALO)             /* 42 h-blurred rows held in LDS */
#define NTX (IMG/TSX)                 /* 8 */
#define NTY (IMG/TSY)                 /* 16 */
#define NBLK (NIMG*NTX*NTY)           /* 6144 blocks / partials */
#define NPIX (16.0 * 3.0 * 512.0 * 512.0)

typedef _Float16 f16;
typedef _Float16 h2 __attribute__((ext_vector_type(2)));

/* packed fp16 {w,w} weights, built on host -> kernarg -> SGPR operands */
struct GaussW { unsigned hw[WIN]; };

__device__ __forceinline__ unsigned pk2(float a, float b) {
    auto h = __builtin_amdgcn_cvt_pkrtz(a, b);
    return __builtin_bit_cast(unsigned, h);
}
__device__ __forceinline__ h2 uph(unsigned u) {
    return __builtin_bit_cast(h2, u);
}
__device__ __forceinline__ unsigned dnh(h2 v) {
    return __builtin_bit_cast(unsigned, v);
}

__global__ void __launch_bounds__(64) zero_kernel(float* out) {
    if (threadIdx.x == 0) out[0] = 0.f;
}

__global__ void __launch_bounds__(64) finish_kernel(float* out) {
    if (threadIdx.x == 0)
        out[0] = 1.0f - out[0] * (float)(1.0 / NPIX);
}

// ---------------- Fused h-blur + v-blur + SSIM, one 64x32 tile per block ----
// R5 post-mortem: packed h-blur cut VALUBusy 60->40% but dur only 78.7->76.4:
// latency-bound.  OccupancyPercent ~51% = only 2 blocks/CU resident at
// 38.4KB LDS (R1's 256-thr variant also pinned at ~2 blocks) -> effective
// LDS pool per CU is far below 160KB after allocation granularity.
// This version halves the tile height: hb[42][32] = 21.5KB -> 4 blocks/CU
// (32 waves/CU) should fit.  Costs +13% phase-1 halo work; tests the
// occupancy theory with one variable changed.
template<int USE_ATOMIC>
__global__ void __launch_bounds__(512, 8) fused_ssim(
        const float* __restrict__ xin, const float* __restrict__ yin,
        float* __restrict__ outp, GaussW W) {
    __shared__ uint4 hb[HR][32];      /* 42 * 512B = 21,504 B */
    __shared__ float wsum[8];
    const int tid = threadIdx.x;
    const int tx = blockIdx.x, ty = blockIdx.y;
    const size_t ibase = (size_t)blockIdx.z * (size_t)(IMG * IMG);
    const float* __restrict__ xb = xin + ibase;
    const float* __restrict__ yb = yin + ibase;

    // ---- phase 1: horizontal blur of image rows ty*32-5 .. ty*32+36 ----
    // 512 thr = 16 colgroups x 32 rows; 2 passes cover the 42 halo'd rows.
    const int cg  = tid & 15;                 /* 4 output cols per thread */
    const int rr  = tid >> 4;                 /* 0..31 */
    const int gx0 = tx * TSX + cg * 4 - HALO; /* 14-col window gx0..gx0+13 */
    const bool cint = (gx0 >= 0) && (gx0 + 13 < IMG);

    #pragma unroll
    for (int it = 0; it < 2; ++it) {
        const int r = it * 32 + rr;           /* 0..63, keep r < 42 */
        if (r < HR) {
            const int gy = ty * TSY - HALO + r;
            if ((unsigned)gy < IMG) {
                const float* xr = xb + (size_t)gy * IMG;
                const float* yr = yb + (size_t)gy * IMG;
                float xv[14], yv[14];
                if (cint) {
                    xv[0] = xr[gx0];  yv[0] = yr[gx0];
                    #pragma unroll
                    for (int q = 0; q < 3; ++q) {     /* 16B-aligned float4s */
                        float4 a = *(const float4*)(xr + gx0 + 1 + 4*q);
                        float4 b = *(const float4*)(yr + gx0 + 1 + 4*q);
                        xv[1+4*q]=a.x; xv[2+4*q]=a.y; xv[3+4*q]=a.z; xv[4+4*q]=a.w;
                        yv[1+4*q]=b.x; yv[2+4*q]=b.y; yv[3+4*q]=b.z; yv[4+4*q]=b.w;
                    }
                    xv[13] = xr[gx0 + 13];  yv[13] = yr[gx0 + 13];
                } else {
                    #pragma unroll
                    for (int j = 0; j < 14; ++j) {
                        int gx = gx0 + j;
                        bool ok = ((unsigned)gx < IMG);
                        xv[j] = ok ? xr[gx] : 0.f;
                        yv[j] = ok ? yr[gx] : 0.f;
                    }
                }
                /* packed h-blur: a0 = blur{x,y}, a1 = blur{x^2+y^2, x*y} */
                h2 a0[4], a1[4];
                #pragma unroll
                for (int o = 0; o < 4; ++o) {
                    a0[o] = (h2){(f16)0, (f16)0};
                    a1[o] = (h2){(f16)0, (f16)0};
                }
                #pragma unroll
                for (int j = 0; j < 14; ++j) {
                    float xs = xv[j], ys = yv[j];
                    float xy = xs * ys;
                    float ss = fmaf(xs, xs, ys * ys);
                    h2 c0 = uph(pk2(xs, ys));
                    h2 c1 = uph(pk2(ss, xy));
                    #pragma unroll
                    for (int o = 0; o < 4; ++o) {
                        int k = j - o;
                        if (k >= 0 && k < WIN) {
                            h2 wk = uph(W.hw[k]);     /* SGPR operand */
                            a0[o] += wk * c0;
                            a1[o] += wk * c1;
                        }
                    }
                }
                /* uint4 = {col even: c0,c1, col odd: c0,c1} */
                uint4 u0, u1;
                u0.x = dnh(a0[0]); u0.y = dnh(a1[0]);
                u0.z = dnh(a0[1]); u0.w = dnh(a1[1]);
                u1.x = dnh(a0[2]); u1.y = dnh(a1[2]);
                u1.z = dnh(a0[3]); u1.w = dnh(a1[3]);
                hb[r][cg]      = u0;          /* cols 4cg,4cg+1 */
                hb[r][cg + 16] = u1;          /* cols 4cg+2,4cg+3 */
            } else {
                uint4 z = make_uint4(0u, 0u, 0u, 0u);
                hb[r][cg]      = z;
                hb[r][cg + 16] = z;
            }
        }
    }
    __syncthreads();

    // ---- phase 2: vertical blur (fp16 packed) + SSIM + block reduce ----
    // 512 thr = 32 col-slots x 16 rowgroups of 2 output rows.  STREAMED:
    // one ds_read_b128 per input row j (12 rows), acc into acc[o][field].
    const int idx = tid & 31;                 /* LDS col-slot (2 cols) */
    const int rbase = (tid >> 5) * 2;         /* first of 12 input rows */

    h2 acc[2][4];
    #pragma unroll
    for (int o = 0; o < 2; ++o)
        #pragma unroll
        for (int f = 0; f < 4; ++f)
            acc[o][f] = (h2){(f16)0, (f16)0};

    #pragma unroll
    for (int j = 0; j < 12; ++j) {
        uint4 u = hb[rbase + j][idx];
        h2 f0 = uph(u.x), f1 = uph(u.y), f2 = uph(u.z), f3 = uph(u.w);
        #pragma unroll
        for (int o = 0; o < 2; ++o) {
            int k = j - o;
            if (k >= 0 && k < WIN) {
                h2 wk = uph(W.hw[k]);         /* SGPR operand */
                acc[o][0] += wk * f0;
                acc[o][1] += wk * f1;
                acc[o][2] += wk * f2;
                acc[o][3] += wk * f3;
            }
        }
    }

    const float C1 = 0.01f * 0.01f;
    const float C2 = 0.03f * 0.03f;
    float local = 0.f;
    #pragma unroll
    for (int o = 0; o < 2; ++o) {
        #pragma unroll
        for (int p = 0; p < 2; ++p) {         /* even col (p=0), odd (p=1) */
            h2 m  = acc[o][2*p];              /* {mu_x, mu_y}   */
            h2 se = acc[o][2*p+1];            /* {E[ss], E[xy]} */
            float mux = (float)m[0];
            float muy = (float)m[1];
            float es  = (float)se[0];
            float exy = (float)se[1];
            float mux2 = mux * mux, muy2 = muy * muy, muxy = mux * muy;
            float num = (2.f * muxy + C1) * (2.f * (exy - muxy) + C2);
            float den = (mux2 + muy2 + C1) * ((es - mux2 - muy2) + C2);
            local += num * __builtin_amdgcn_rcpf(den + 1e-8f);
        }
    }

    #pragma unroll
    for (int off = 32; off > 0; off >>= 1)
        local += __shfl_down(local, off, 64);
    if ((tid & 63) == 0) wsum[tid >> 6] = local;
    __syncthreads();
    if (tid == 0) {
        float bs = 0.f;
        #pragma unroll
        for (int wv = 0; wv < 8; ++wv) bs += wsum[wv];
        if (USE_ATOMIC) {
            atomicAdd(outp, bs);
        } else {
            int bid = (blockIdx.z * NTY + blockIdx.y) * NTX + blockIdx.x;
            outp[bid] = bs;
        }
    }
}

// ---------------- Final reduce: 6144 partials -> out[0], one block ----------
__global__ void __launch_bounds__(256) reduce_kernel(
        const float* __restrict__ partial, float* __restrict__ out) {
    __shared__ float wsum[4];
    const int tid = threadIdx.x;
    float s = 0.f;
    for (int i = tid; i < NBLK; i += 256) s += partial[i];
    #pragma unroll
    for (int off = 32; off > 0; off >>= 1)
        s += __shfl_down(s, off, 64);
    if ((tid & 63) == 0) wsum[tid >> 6] = s;
    __syncthreads();
    if (tid == 0)
        out[0] = 1.0f - (wsum[0] + wsum[1] + wsum[2] + wsum[3]) * (float)(1.0 / NPIX);
}

extern "C" void kernel_launch(void* const* d_in, const int* in_sizes, int n_in,
                              void* d_out, int out_size, void* d_ws, size_t ws_size,
                              hipStream_t stream) {
    const float* x = (const float*)d_in[0];
    const float* y = (const float*)d_in[1];
    float* out = (float*)d_out;

    /* fp32 Gaussian weights */
    double g[WIN], s = 0.0;
    for (int i = 0; i < WIN; ++i) {
        double d = (double)(i - WIN / 2);
        g[i] = exp(-(d * d) / (2.0 * 1.5 * 1.5));
        s += g[i];
    }
    float wf[WIN];
    for (int i = 0; i < WIN; ++i) wf[i] = (float)(g[i] / s);

    /* pack to fp16 {w,w}; renormalize center tap so fp16 weight sum == 1 */
    GaussW gw;
    _Float16 wh[WIN];
    double hsum = 0.0;
    for (int i = 0; i < WIN; ++i) { wh[i] = (_Float16)wf[i]; hsum += (double)(float)wh[i]; }
    wh[WIN/2] = (_Float16)((float)wh[WIN/2] + (float)(1.0 - hsum));
    for (int i = 0; i < WIN; ++i) {
        unsigned short b = __builtin_bit_cast(unsigned short, wh[i]);
        gw.hw[i] = (unsigned)b | ((unsigned)b << 16);
    }

    if (ws_size >= (size_t)NBLK * sizeof(float)) {
        float* partial = (float*)d_ws;
        hipLaunchKernelGGL((fused_ssim<0>), dim3(NTX, NTY, NIMG), dim3(512),
                           0, stream, x, y, partial, gw);
        hipLaunchKernelGGL(reduce_kernel, dim3(1), dim3(256), 0, stream,
                           partial, out);
    } else {
        hipLaunchKernelGGL(zero_kernel, dim3(1), dim3(64), 0, stream, out);
        hipLaunchKernelGGL((fused_ssim<1>), dim3(NTX, NTY, NIMG), dim3(512),
                           0, stream, x, y, out, gw);
        hipLaunchKernelGGL(finish_kernel, dim3(1), dim3(64), 0, stream, out);
    }
}

// Round 9
// 160.673 us; speedup vs baseline: 1.0766x; 1.0766x over previous
//
#include <hip/hip_runtime.h>
#include <cmath>

#define WIN 11
#define HALO 5
#define IMG 512
#define NIMG 48
#define TS 64                         /* output tile: 64x64 */
#define HR (TS + 2*HALO)              /* 74 h-blurred rows held in LDS */
#define NTILE (IMG/TS)                /* 8 tiles per axis */
#define NBLK (NIMG*NTILE*NTILE)       /* 3072 blocks / partials */
#define NPIX (16.0 * 3.0 * 512.0 * 512.0)

typedef _Float16 f16;
typedef _Float16 h2 __attribute__((ext_vector_type(2)));

/* packed fp16 {w,w} weights, built on host -> kernarg -> SGPR operands */
struct GaussW { unsigned hw[WIN]; };

__device__ __forceinline__ unsigned pk2(float a, float b) {
    auto h = __builtin_amdgcn_cvt_pkrtz(a, b);
    return __builtin_bit_cast(unsigned, h);
}
__device__ __forceinline__ h2 uph(unsigned u) {
    return __builtin_bit_cast(h2, u);
}
__device__ __forceinline__ unsigned dnh(h2 v) {
    return __builtin_bit_cast(unsigned, v);
}

__global__ void __launch_bounds__(64) zero_kernel(float* out) {
    if (threadIdx.x == 0) out[0] = 0.f;
}

__global__ void __launch_bounds__(64) finish_kernel(float* out) {
    if (threadIdx.x == 0)
        out[0] = 1.0f - out[0] * (float)(1.0 / NPIX);
}

// ---------------- Fused h-blur + v-blur + SSIM, one 64x64 tile per block ----
// R6 post-mortem: residency is pinned at ~2 WORKGROUPS/CU independent of
// block size (256thr->2.2, 512thr->2) and LDS (38.4KB->2, 22KB->2).  Waves
// stall >50% (phase-1 load latency at VGPR=24 + barrier) and 4 waves/SIMD
// can't hide it -> VALUBusy 43%.
// This version: 1024-thread blocks.  If the cap is 2 WGs/CU, that's
// 2 x 16 waves = 32 waves/CU = full occupancy (double the hiding pool).
// Tile back to 64x64 (best halo amortization, hb=37.9KB proven 2-resident).
template<int USE_ATOMIC>
__global__ void __launch_bounds__(1024, 8) fused_ssim(
        const float* __restrict__ xin, const float* __restrict__ yin,
        float* __restrict__ outp, GaussW W) {
    __shared__ uint4 hb[HR][32];      /* 74 * 512B = 37,888 B */
    __shared__ float wsum[16];
    const int tid = threadIdx.x;
    const int tx = blockIdx.x, ty = blockIdx.y;
    const size_t ibase = (size_t)blockIdx.z * (size_t)(IMG * IMG);
    const float* __restrict__ xb = xin + ibase;
    const float* __restrict__ yb = yin + ibase;

    // ---- phase 1: horizontal blur of image rows ty*64-5 .. ty*64+68 ----
    // 1024 thr = 16 colgroups x 64 rows; pass 2 covers rows 64..73.
    const int cg  = tid & 15;                 /* 4 output cols per thread */
    const int rr  = tid >> 4;                 /* 0..63 */
    const int gx0 = tx * TS + cg * 4 - HALO;  /* 14-col window gx0..gx0+13 */
    const bool cint = (gx0 >= 0) && (gx0 + 13 < IMG);

    #pragma unroll
    for (int it = 0; it < 2; ++it) {
        const int r = it * 64 + rr;           /* 0..127, keep r < 74 */
        if (r < HR) {
            const int gy = ty * TS - HALO + r;
            if ((unsigned)gy < IMG) {
                const float* xr = xb + (size_t)gy * IMG;
                const float* yr = yb + (size_t)gy * IMG;
                float xv[14], yv[14];
                if (cint) {
                    xv[0] = xr[gx0];  yv[0] = yr[gx0];
                    #pragma unroll
                    for (int q = 0; q < 3; ++q) {     /* 16B-aligned float4s */
                        float4 a = *(const float4*)(xr + gx0 + 1 + 4*q);
                        float4 b = *(const float4*)(yr + gx0 + 1 + 4*q);
                        xv[1+4*q]=a.x; xv[2+4*q]=a.y; xv[3+4*q]=a.z; xv[4+4*q]=a.w;
                        yv[1+4*q]=b.x; yv[2+4*q]=b.y; yv[3+4*q]=b.z; yv[4+4*q]=b.w;
                    }
                    xv[13] = xr[gx0 + 13];  yv[13] = yr[gx0 + 13];
                } else {
                    #pragma unroll
                    for (int j = 0; j < 14; ++j) {
                        int gx = gx0 + j;
                        bool ok = ((unsigned)gx < IMG);
                        xv[j] = ok ? xr[gx] : 0.f;
                        yv[j] = ok ? yr[gx] : 0.f;
                    }
                }
                /* packed h-blur: a0 = blur{x,y}, a1 = blur{x^2+y^2, x*y} */
                h2 a0[4], a1[4];
                #pragma unroll
                for (int o = 0; o < 4; ++o) {
                    a0[o] = (h2){(f16)0, (f16)0};
                    a1[o] = (h2){(f16)0, (f16)0};
                }
                #pragma unroll
                for (int j = 0; j < 14; ++j) {
                    float xs = xv[j], ys = yv[j];
                    float xy = xs * ys;
                    float ss = fmaf(xs, xs, ys * ys);
                    h2 c0 = uph(pk2(xs, ys));
                    h2 c1 = uph(pk2(ss, xy));
                    #pragma unroll
                    for (int o = 0; o < 4; ++o) {
                        int k = j - o;
                        if (k >= 0 && k < WIN) {
                            h2 wk = uph(W.hw[k]);     /* SGPR operand */
                            a0[o] += wk * c0;
                            a1[o] += wk * c1;
                        }
                    }
                }
                /* uint4 = {col even: c0,c1, col odd: c0,c1} */
                uint4 u0, u1;
                u0.x = dnh(a0[0]); u0.y = dnh(a1[0]);
                u0.z = dnh(a0[1]); u0.w = dnh(a1[1]);
                u1.x = dnh(a0[2]); u1.y = dnh(a1[2]);
                u1.z = dnh(a0[3]); u1.w = dnh(a1[3]);
                hb[r][cg]      = u0;          /* cols 4cg,4cg+1 */
                hb[r][cg + 16] = u1;          /* cols 4cg+2,4cg+3 */
            } else {
                uint4 z = make_uint4(0u, 0u, 0u, 0u);
                hb[r][cg]      = z;
                hb[r][cg + 16] = z;
            }
        }
    }
    __syncthreads();

    // ---- phase 2: vertical blur (fp16 packed) + SSIM + block reduce ----
    // 1024 thr = 32 col-slots x 32 rowgroups of 2 output rows.  STREAMED:
    // one ds_read_b128 per input row j (12 rows), acc into acc[o][field].
    const int idx = tid & 31;                 /* LDS col-slot (2 cols) */
    const int rbase = (tid >> 5) * 2;         /* first of 12 input rows */

    h2 acc[2][4];
    #pragma unroll
    for (int o = 0; o < 2; ++o)
        #pragma unroll
        for (int f = 0; f < 4; ++f)
            acc[o][f] = (h2){(f16)0, (f16)0};

    #pragma unroll
    for (int j = 0; j < 12; ++j) {
        uint4 u = hb[rbase + j][idx];
        h2 f0 = uph(u.x), f1 = uph(u.y), f2 = uph(u.z), f3 = uph(u.w);
        #pragma unroll
        for (int o = 0; o < 2; ++o) {
            int k = j - o;
            if (k >= 0 && k < WIN) {
                h2 wk = uph(W.hw[k]);         /* SGPR operand */
                acc[o][0] += wk * f0;
                acc[o][1] += wk * f1;
                acc[o][2] += wk * f2;
                acc[o][3] += wk * f3;
            }
        }
    }

    const float C1 = 0.01f * 0.01f;
    const float C2 = 0.03f * 0.03f;
    float local = 0.f;
    #pragma unroll
    for (int o = 0; o < 2; ++o) {
        #pragma unroll
        for (int p = 0; p < 2; ++p) {         /* even col (p=0), odd (p=1) */
            h2 m  = acc[o][2*p];              /* {mu_x, mu_y}   */
            h2 se = acc[o][2*p+1];            /* {E[ss], E[xy]} */
            float mux = (float)m[0];
            float muy = (float)m[1];
            float es  = (float)se[0];
            float exy = (float)se[1];
            float mux2 = mux * mux, muy2 = muy * muy, muxy = mux * muy;
            float num = (2.f * muxy + C1) * (2.f * (exy - muxy) + C2);
            float den = (mux2 + muy2 + C1) * ((es - mux2 - muy2) + C2);
            local += num * __builtin_amdgcn_rcpf(den + 1e-8f);
        }
    }

    #pragma unroll
    for (int off = 32; off > 0; off >>= 1)
        local += __shfl_down(local, off, 64);
    if ((tid & 63) == 0) wsum[tid >> 6] = local;
    __syncthreads();
    if (tid == 0) {
        float bs = 0.f;
        #pragma unroll
        for (int wv = 0; wv < 16; ++wv) bs += wsum[wv];
        if (USE_ATOMIC) {
            atomicAdd(outp, bs);
        } else {
            int bid = (blockIdx.z * NTILE + blockIdx.y) * NTILE + blockIdx.x;
            outp[bid] = bs;
        }
    }
}

// ---------------- Final reduce: 3072 partials -> out[0], one block ----------
__global__ void __launch_bounds__(256) reduce_kernel(
        const float* __restrict__ partial, float* __restrict__ out) {
    __shared__ float wsum[4];
    const int tid = threadIdx.x;
    float s = 0.f;
    for (int i = tid; i < NBLK; i += 256) s += partial[i];
    #pragma unroll
    for (int off = 32; off > 0; off >>= 1)
        s += __shfl_down(s, off, 64);
    if ((tid & 63) == 0) wsum[tid >> 6] = s;
    __syncthreads();
    if (tid == 0)
        out[0] = 1.0f - (wsum[0] + wsum[1] + wsum[2] + wsum[3]) * (float)(1.0 / NPIX);
}

extern "C" void kernel_launch(void* const* d_in, const int* in_sizes, int n_in,
                              void* d_out, int out_size, void* d_ws, size_t ws_size,
                              hipStream_t stream) {
    const float* x = (const float*)d_in[0];
    const float* y = (const float*)d_in[1];
    float* out = (float*)d_out;

    /* fp32 Gaussian weights */
    double g[WIN], s = 0.0;
    for (int i = 0; i < WIN; ++i) {
        double d = (double)(i - WIN / 2);
        g[i] = exp(-(d * d) / (2.0 * 1.5 * 1.5));
        s += g[i];
    }
    float wf[WIN];
    for (int i = 0; i < WIN; ++i) wf[i] = (float)(g[i] / s);

    /* pack to fp16 {w,w}; renormalize center tap so fp16 weight sum == 1 */
    GaussW gw;
    _Float16 wh[WIN];
    double hsum = 0.0;
    for (int i = 0; i < WIN; ++i) { wh[i] = (_Float16)wf[i]; hsum += (double)(float)wh[i]; }
    wh[WIN/2] = (_Float16)((float)wh[WIN/2] + (float)(1.0 - hsum));
    for (int i = 0; i < WIN; ++i) {
        unsigned short b = __builtin_bit_cast(unsigned short, wh[i]);
        gw.hw[i] = (unsigned)b | ((unsigned)b << 16);
    }

    if (ws_size >= (size_t)NBLK * sizeof(float)) {
        float* partial = (float*)d_ws;
        hipLaunchKernelGGL((fused_ssim<0>), dim3(NTILE, NTILE, NIMG), dim3(1024),
                           0, stream, x, y, partial, gw);
        hipLaunchKernelGGL(reduce_kernel, dim3(1), dim3(256), 0, stream,
                           partial, out);
    } else {
        hipLaunchKernelGGL(zero_kernel, dim3(1), dim3(64), 0, stream, out);
        hipLaunchKernelGGL((fused_ssim<1>), dim3(NTILE, NTILE, NIMG), dim3(1024),
                           0, stream, x, y, out, gw);
        hipLaunchKernelGGL(finish_kernel, dim3(1), dim3(64), 0, stream, out);
    }
}

// Round 10
// 149.539 us; speedup vs baseline: 1.1568x; 1.0745x over previous
//
#include <hip/hip_runtime.h>
#include <cmath>

#define WIN 11
#define HALO 5
#define IMG 512
#define NIMG 48
#define TS 64                         /* output tile: 64x64 */
#define HR (TS + 2*HALO)              /* 74 h-blurred rows held in LDS */
#define NTILE (IMG/TS)                /* 8 tiles per axis */
#define NTT (NIMG*NTILE*NTILE)        /* 3072 tiles total */
#define PBLK 512                      /* persistent blocks */
#define TPB (NTT/PBLK)                /* 6 tiles per block */
#define NPIX (16.0 * 3.0 * 512.0 * 512.0)

typedef _Float16 f16;
typedef _Float16 h2 __attribute__((ext_vector_type(2)));

/* packed fp16 {w,w} weights, built on host -> kernarg -> SGPR operands */
struct GaussW { unsigned hw[WIN]; };

__device__ __forceinline__ unsigned pk2(float a, float b) {
    auto h = __builtin_amdgcn_cvt_pkrtz(a, b);
    return __builtin_bit_cast(unsigned, h);
}
__device__ __forceinline__ h2 uph(unsigned u) {
    return __builtin_bit_cast(h2, u);
}
__device__ __forceinline__ unsigned dnh(h2 v) {
    return __builtin_bit_cast(unsigned, v);
}

__global__ void __launch_bounds__(64) zero_kernel(float* out) {
    if (threadIdx.x == 0) out[0] = 0.f;
}

__global__ void __launch_bounds__(64) finish_kernel(float* out) {
    if (threadIdx.x == 0)
        out[0] = 1.0f - out[0] * (float)(1.0 / NPIX);
}

// ------------- Persistent fused SSIM: 512 blocks x 6 tiles, pipelined -------
// R9 post-mortem: occupancy hard-caps at ~16 waves/CU for any block shape;
// block critical path is ~6us vs ~1us VALU+~1us LDS content -> exposed
// global latency + per-block prologue dominate (3072 short-lived blocks).
// This version: persistent blocks; per iteration phase2(tile t) computes
// from LDS while tile t+1's pixels already sit in registers and tile t+2's
// loads are issued (T14 async-stage).  Latency paid once per block, not per
// tile.  Phase 1 is single-pass (592 thr x 8 cols, 18-col window) so one
// 36-VGPR register buffer carries the prefetch across the pipeline.
template<int USE_ATOMIC>
__global__ void __launch_bounds__(1024, 4) fused_ssim(
        const float* __restrict__ xin, const float* __restrict__ yin,
        float* __restrict__ outp, GaussW W) {
    __shared__ uint4 hb[HR][32];      /* 74 * 512B = 37,888 B */
    __shared__ float wsum[16];
    const int tid = threadIdx.x;
    /* phase-1 mapping: 8 cols/thread, 74 rows -> threads 0..591 active */
    const int cg = tid & 7;
    const int r  = tid >> 3;          /* 0..127, active if r < HR */
    /* phase-2 mapping: 32 col-pair slots x 32 rowgroups x 2 rows */
    const int idx   = tid & 31;
    const int rbase = (tid >> 5) * 2;

    const int t0 = blockIdx.x * TPB;

    float xv[18], yv[18];             /* prefetch buffer (held across phase2) */
    float local = 0.f;

    /* ---- issue global loads for tile t into xv/yv (registers) ---- */
    auto prefetch = [&](int t) {
        if (r >= HR) return;
        const int tg  = t0 + t;
        const int img = tg >> 6;
        const int rem = tg & 63;
        const int ty  = rem >> 3;
        const int tx  = rem & 7;
        const float* xb = xin + (size_t)img * (IMG * IMG);
        const float* yb = yin + (size_t)img * (IMG * IMG);
        const int gy  = ty * TS - HALO + r;
        const int gx0 = tx * TS + cg * 8 - HALO;   /* 18-col window */
        const bool rowok = ((unsigned)gy < IMG);
        const float* xr = xb + (size_t)gy * IMG;
        const float* yr = yb + (size_t)gy * IMG;
        if (rowok && gx0 >= 0 && gx0 + 17 < IMG) {
            xv[0] = xr[gx0];  yv[0] = yr[gx0];
            #pragma unroll
            for (int q = 0; q < 4; ++q) {          /* 16B-aligned float4s */
                float4 a = *(const float4*)(xr + gx0 + 1 + 4*q);
                float4 b = *(const float4*)(yr + gx0 + 1 + 4*q);
                xv[1+4*q]=a.x; xv[2+4*q]=a.y; xv[3+4*q]=a.z; xv[4+4*q]=a.w;
                yv[1+4*q]=b.x; yv[2+4*q]=b.y; yv[3+4*q]=b.z; yv[4+4*q]=b.w;
            }
            xv[17] = xr[gx0 + 17];  yv[17] = yr[gx0 + 17];
        } else {
            #pragma unroll
            for (int j = 0; j < 18; ++j) {
                int gx = gx0 + j;
                bool ok = rowok && ((unsigned)gx < IMG);
                xv[j] = ok ? xr[gx] : 0.f;
                yv[j] = ok ? yr[gx] : 0.f;
            }
        }
    };

    /* ---- packed fp16 h-blur of the register window -> LDS row ---- */
    auto hblur = [&]() {
        if (r >= HR) return;
        h2 a0[8], a1[8];
        #pragma unroll
        for (int o = 0; o < 8; ++o) {
            a0[o] = (h2){(f16)0, (f16)0};
            a1[o] = (h2){(f16)0, (f16)0};
        }
        #pragma unroll
        for (int j = 0; j < 18; ++j) {
            float xs = xv[j], ys = yv[j];
            h2 c0 = uph(pk2(xs, ys));
            h2 c1 = uph(pk2(fmaf(xs, xs, ys * ys), xs * ys));
            #pragma unroll
            for (int o = 0; o < 8; ++o) {
                int k = j - o;
                if (k >= 0 && k < WIN) {
                    h2 wk = uph(W.hw[k]);          /* SGPR operand */
                    a0[o] += wk * c0;
                    a1[o] += wk * c1;
                }
            }
        }
        /* col-pair p of this thread -> slot cg + 8p (16B lane stride) */
        #pragma unroll
        for (int p = 0; p < 4; ++p) {
            uint4 u;
            u.x = dnh(a0[2*p]);     u.y = dnh(a1[2*p]);
            u.z = dnh(a0[2*p + 1]); u.w = dnh(a1[2*p + 1]);
            hb[r][cg + 8*p] = u;
        }
    };

    /* ---- v-blur + SSIM for current LDS tile, accumulate into local ---- */
    auto phase2 = [&]() {
        h2 acc[2][4];
        #pragma unroll
        for (int o = 0; o < 2; ++o)
            #pragma unroll
            for (int f = 0; f < 4; ++f)
                acc[o][f] = (h2){(f16)0, (f16)0};
        #pragma unroll
        for (int j = 0; j < 12; ++j) {
            uint4 u = hb[rbase + j][idx];
            h2 f0 = uph(u.x), f1 = uph(u.y), f2 = uph(u.z), f3 = uph(u.w);
            #pragma unroll
            for (int o = 0; o < 2; ++o) {
                int k = j - o;
                if (k >= 0 && k < WIN) {
                    h2 wk = uph(W.hw[k]);
                    acc[o][0] += wk * f0;
                    acc[o][1] += wk * f1;
                    acc[o][2] += wk * f2;
                    acc[o][3] += wk * f3;
                }
            }
        }
        const float C1 = 0.01f * 0.01f;
        const float C2 = 0.03f * 0.03f;
        #pragma unroll
        for (int o = 0; o < 2; ++o) {
            #pragma unroll
            for (int p = 0; p < 2; ++p) {
                h2 m  = acc[o][2*p];               /* {mu_x, mu_y}   */
                h2 se = acc[o][2*p + 1];           /* {E[ss], E[xy]} */
                float mux = (float)m[0];
                float muy = (float)m[1];
                float es  = (float)se[0];
                float exy = (float)se[1];
                float mux2 = mux*mux, muy2 = muy*muy, muxy = mux*muy;
                float num = (2.f*muxy + C1) * (2.f*(exy - muxy) + C2);
                float den = (mux2 + muy2 + C1) * ((es - mux2 - muy2) + C2);
                local += num * __builtin_amdgcn_rcpf(den + 1e-8f);
            }
        }
    };

    /* ---- pipeline: prologue pays load latency once ---- */
    prefetch(0);
    hblur();                          /* consumes tile 0 regs */
    prefetch(1);                      /* tile 1 in flight/regs */
    __syncthreads();

    for (int t = 0; t < TPB; ++t) {
        phase2();                     /* tile t from LDS; t+1 loads hidden */
        if (t + 1 < TPB) {
            __syncthreads();          /* phase2 reads done */
            hblur();                  /* tile t+1 regs -> LDS */
            if (t + 2 < TPB) {
                prefetch(t + 2);      /* issue next loads */
                __builtin_amdgcn_sched_barrier(0);  /* pin issue point */
            }
            __syncthreads();          /* hb ready */
        }
    }

    /* ---- block reduce: one partial per block ---- */
    #pragma unroll
    for (int off = 32; off > 0; off >>= 1)
        local += __shfl_down(local, off, 64);
    if ((tid & 63) == 0) wsum[tid >> 6] = local;
    __syncthreads();
    if (tid == 0) {
        float bs = 0.f;
        #pragma unroll
        for (int wv = 0; wv < 16; ++wv) bs += wsum[wv];
        if (USE_ATOMIC) {
            atomicAdd(outp, bs);
        } else {
            outp[blockIdx.x] = bs;
        }
    }
}

// ---------------- Final reduce: 512 partials -> out[0], one block -----------
__global__ void __launch_bounds__(256) reduce_kernel(
        const float* __restrict__ partial, float* __restrict__ out) {
    __shared__ float wsum[4];
    const int tid = threadIdx.x;
    float s = 0.f;
    for (int i = tid; i < PBLK; i += 256) s += partial[i];
    #pragma unroll
    for (int off = 32; off > 0; off >>= 1)
        s += __shfl_down(s, off, 64);
    if ((tid & 63) == 0) wsum[tid >> 6] = s;
    __syncthreads();
    if (tid == 0)
        out[0] = 1.0f - (wsum[0] + wsum[1] + wsum[2] + wsum[3]) * (float)(1.0 / NPIX);
}

extern "C" void kernel_launch(void* const* d_in, const int* in_sizes, int n_in,
                              void* d_out, int out_size, void* d_ws, size_t ws_size,
                              hipStream_t stream) {
    const float* x = (const float*)d_in[0];
    const float* y = (const float*)d_in[1];
    float* out = (float*)d_out;

    /* fp32 Gaussian weights */
    double g[WIN], s = 0.0;
    for (int i = 0; i < WIN; ++i) {
        double d = (double)(i - WIN / 2);
        g[i] = exp(-(d * d) / (2.0 * 1.5 * 1.5));
        s += g[i];
    }
    float wf[WIN];
    for (int i = 0; i < WIN; ++i) wf[i] = (float)(g[i] / s);

    /* pack to fp16 {w,w}; renormalize center tap so fp16 weight sum == 1 */
    GaussW gw;
    _Float16 wh[WIN];
    double hsum = 0.0;
    for (int i = 0; i < WIN; ++i) { wh[i] = (_Float16)wf[i]; hsum += (double)(float)wh[i]; }
    wh[WIN/2] = (_Float16)((float)wh[WIN/2] + (float)(1.0 - hsum));
    for (int i = 0; i < WIN; ++i) {
        unsigned short b = __builtin_bit_cast(unsigned short, wh[i]);
        gw.hw[i] = (unsigned)b | ((unsigned)b << 16);
    }

    if (ws_size >= (size_t)PBLK * sizeof(float)) {
        float* partial = (float*)d_ws;
        hipLaunchKernelGGL((fused_ssim<0>), dim3(PBLK), dim3(1024),
                           0, stream, x, y, partial, gw);
        hipLaunchKernelGGL(reduce_kernel, dim3(1), dim3(256), 0, stream,
                           partial, out);
    } else {
        hipLaunchKernelGGL(zero_kernel, dim3(1), dim3(64), 0, stream, out);
        hipLaunchKernelGGL((fused_ssim<1>), dim3(PBLK), dim3(1024),
                           0, stream, x, y, out, gw);
        hipLaunchKernelGGL(finish_kernel, dim3(1), dim3(64), 0, stream, out);
    }
}